// Round 4
// baseline (684.101 us; speedup 1.0000x reference)
//
#include <hip/hip_runtime.h>

#define NF 768
#define D1 10
#define D2 128
#define BM 64

typedef __attribute__((ext_vector_type(8))) short bf16x8;
typedef __attribute__((ext_vector_type(16))) float f32x16;

static __device__ __forceinline__ float sigf(float v){ return 1.0f/(1.0f+__expf(-v)); }
static __device__ __forceinline__ float tanhfast(float v){ return 2.0f/(1.0f+__expf(-2.0f*v)) - 1.0f; }
static __device__ __forceinline__ short f2bf(float f){
    unsigned u = __float_as_uint(f);
    u += 0x7fffu + ((u>>16)&1u);
    return (short)(u>>16);
}

// ---- degree counts ----
__global__ void k_deg(const int* __restrict__ dst, int* __restrict__ cnt, int E){
    int e = blockIdx.x*256 + threadIdx.x;
    if(e<E) atomicAdd(&cnt[dst[e]], 1);
}

// ---- scan (rowptr/rowcur) + dinv fused, single block ----
__global__ __launch_bounds__(256) void k_scan(const int* __restrict__ cnt,
                                              int* __restrict__ rowptr, int* __restrict__ rowcur,
                                              float* __restrict__ dinv, int N, int E){
    __shared__ int part[256];
    int t = threadIdx.x;
    int C = (N+255)/256;
    int lo = t*C, hi = lo+C; if(hi>N) hi=N; if(lo>N) lo=N;
    int s=0;
    for(int i=lo;i<hi;i++) s += cnt[i];
    part[t]=s;
    __syncthreads();
    if(t==0){
        int run=0;
        for(int i=0;i<256;i++){ int v=part[i]; part[i]=run; run+=v; }
        rowptr[N]=E;
    }
    __syncthreads();
    int run = part[t];
    for(int i=lo;i<hi;i++){
        rowptr[i]=run; rowcur[i]=run; run += cnt[i];
        dinv[i] = rsqrtf((float)cnt[i] + 1.0f);
    }
}

__global__ void k_fill(const int* __restrict__ src, const int* __restrict__ dst,
                       const float* __restrict__ dinv, int* __restrict__ rowcur,
                       int* __restrict__ esrc, float* __restrict__ enorm, int E){
    int e = blockIdx.x*256 + threadIdx.x;
    if(e>=E) return;
    int s=src[e], d=dst[e];
    int pos = atomicAdd(&rowcur[d], 1);
    esrc[pos]=s;
    enorm[pos]=dinv[s]*dinv[d];
}

// ---- h1 = x @ W1, float4 loads, transposed W tile (conflict-free b128 reads) ----
__global__ __launch_bounds__(256) void k_h1(const float* __restrict__ x,
                                            const float* __restrict__ W1,
                                            float* __restrict__ h1, int N){
    __shared__ float wt[D1*NF];
    for(int idx=threadIdx.x; idx<NF*D1; idx+=256){
        int k=idx/D1, c=idx-k*D1;
        wt[c*NF+k]=W1[idx];
    }
    __syncthreads();
    int row = blockIdx.x*4 + (threadIdx.x>>6);
    int lane = threadIdx.x&63;
    if(row>=N) return;
    const float4* xr = (const float4*)(x + (size_t)row*NF);
    float acc[D1];
#pragma unroll
    for(int c=0;c<D1;c++) acc[c]=0.f;
#pragma unroll
    for(int i=0;i<3;i++){
        float4 v = xr[lane + 64*i];
#pragma unroll
        for(int c=0;c<D1;c++){
            float4 w = *(const float4*)&wt[c*NF + (lane+64*i)*4];
            acc[c] += v.x*w.x + v.y*w.y + v.z*w.z + v.w*w.w;
        }
    }
#pragma unroll
    for(int c=0;c<D1;c++){
        float v=acc[c];
#pragma unroll
        for(int off=32;off;off>>=1) v += __shfl_down(v,off,64);
        acc[c]=v;
    }
    if(lane==0){
#pragma unroll
        for(int c=0;c<D1;c++) h1[(size_t)row*D1+c]=acc[c];
    }
}

// ---- layer-1 aggregation via CSR gather, fused relu. One wave per node ----
__global__ __launch_bounds__(256) void k_gath1(const float* __restrict__ h1,
        const int* __restrict__ rowptr, const int* __restrict__ esrc,
        const float* __restrict__ enorm, const float* __restrict__ dinv,
        const float* __restrict__ b1, float* __restrict__ h, int N){
    int node = blockIdx.x*4 + (threadIdx.x>>6);
    int lane = threadIdx.x&63;
    if(node>=N) return;
    int e0=rowptr[node], e1=rowptr[node+1];
    float acc[D1];
#pragma unroll
    for(int c=0;c<D1;c++) acc[c]=0.f;
    for(int e=e0+lane; e<e1; e+=64){
        int s=esrc[e]; float w=enorm[e];
        const float* hr = h1 + (size_t)s*D1;
#pragma unroll
        for(int c=0;c<D1;c++) acc[c] += hr[c]*w;
    }
    if(lane==0){
        float di=dinv[node], d2=di*di;
        const float* hr = h1 + (size_t)node*D1;
#pragma unroll
        for(int c=0;c<D1;c++) acc[c] += hr[c]*d2;
    }
#pragma unroll
    for(int c=0;c<D1;c++){
        float v=acc[c];
#pragma unroll
        for(int off=32;off;off>>=1) v += __shfl_down(v,off,64);
        acc[c]=v;
    }
    if(lane==0){
#pragma unroll
        for(int c=0;c<D1;c++){
            float v = acc[c] + b1[c];
            h[(size_t)node*D1+c] = v>0.f ? v : 0.f;
        }
    }
}

__global__ __launch_bounds__(128) void k_hz(const float* __restrict__ h,
                                            const float* __restrict__ W2,
                                            float* __restrict__ hz, int N){
    __shared__ float w2s[D1*D2];
    int j = threadIdx.x;
    for(int i=j;i<D1*D2;i+=128) w2s[i]=W2[i];
    __syncthreads();
    int n = blockIdx.x;
    if(n>=N) return;
    const float* hr = h + (size_t)n*D1;
    float acc=0.f;
#pragma unroll
    for(int k=0;k<D1;k++) acc += hr[k]*w2s[k*D2+j];
    hz[(size_t)n*D2+j]=acc;
}

// ---- layer-2 CSR gather (fused zfin), writes bf16 zb table ----
__global__ __launch_bounds__(128) void k_gath2(const float* __restrict__ hz,
        const int* __restrict__ rowptr, const int* __restrict__ esrc,
        const float* __restrict__ enorm, const float* __restrict__ dinv,
        const float* __restrict__ b2, ushort* __restrict__ zb, int N){
    int n = blockIdx.x;
    int c = threadIdx.x;
    int e0 = rowptr[n], e1 = rowptr[n+1];
    float di = dinv[n];
    float acc = hz[(size_t)n*D2+c]*di*di + b2[c];
    int e = e0;
    for(; e+1<e1; e+=2){
        int s0=esrc[e], s1=esrc[e+1];
        float w0=enorm[e], w1=enorm[e+1];
        acc += hz[(size_t)s0*D2+c]*w0 + hz[(size_t)s1*D2+c]*w1;
    }
    if(e<e1) acc += hz[(size_t)esrc[e]*D2+c]*enorm[e];
    zb[(size_t)n*D2+c] = (ushort)f2bf(acc);
}

// ---- B fragment image over FULL K=1024: 12 frags x 64 ks16 x 64 lanes x 8 bf16 (786 KB) ----
// frag f = wn*3+gi: gate col = gbase(gi)+wn*32+(l&31); k = ks16*16 + (l>>5)*8 + j
__global__ void k_wimgB(const float* __restrict__ Wih, ushort* __restrict__ img){
    int gid = blockIdx.x*256 + threadIdx.x;        // 12*64*64 = 49152
    if(gid >= 12*64*64) return;
    int l = gid & 63;
    int ks16 = (gid>>6) & 63;
    int f = gid >> 12;
    int dd = l & 31, kb = l>>5;
    int wn = f/3, gi = f - wn*3;
    int gbase = (gi==0)?0:((gi==1)?256:384);
    int wrow = gbase + wn*32 + dd;
    int k = ks16*16 + kb*8;
    const float* p = Wih + (size_t)wrow*1024 + k;
    float4 v0=*(const float4*)p, v1=*(const float4*)(p+4);
    bf16x8 o;
    o[0]=f2bf(v0.x); o[1]=f2bf(v0.y); o[2]=f2bf(v0.z); o[3]=f2bf(v0.w);
    o[4]=f2bf(v1.x); o[5]=f2bf(v1.y); o[6]=f2bf(v1.z); o[7]=f2bf(v1.w);
    *(bf16x8*)(img + (size_t)gid*8) = o;
}

// ---- barrier-free fused GEMM + LSTM. feat = [z_h | r_emb | z_t] @ W(1024) ----
__global__ __launch_bounds__(256) void k_big(
    const float* __restrict__ remb, const ushort* __restrict__ img,
    const ushort* __restrict__ zb, const float* __restrict__ b_ih,
    const float* __restrict__ b_hh, const int* __restrict__ trip,
    float* __restrict__ score, int T)
{
    __shared__ float rowsum[BM];
    int tid=threadIdx.x, lane=tid&63, wn=tid>>6;
    int l31=lane&31, lh=lane>>5;
    int t0=blockIdx.x*BM;
    if(tid<BM) rowsum[tid]=0.f;
    __syncthreads();

    int th[2], tt[2];
    size_t rbase[2];
#pragma unroll
    for(int m=0;m<2;m++){
        int t = t0 + l31 + m*32; if(t>=T) t=T-1;
        rbase[m] = (size_t)t*NF;
        th[m]=trip[3*t]; tt[m]=trip[3*t+2];
    }
    const float* ra0 = remb + rbase[0] + lh*8;
    const float* ra1 = remb + rbase[1] + lh*8;
    const ushort* wb0 = img + ((size_t)(wn*3+0)*64*64 + lane)*8;
    const ushort* wb1 = img + ((size_t)(wn*3+1)*64*64 + lane)*8;
    const ushort* wb2 = img + ((size_t)(wn*3+2)*64*64 + lane)*8;

    f32x16 acc[2][3];
    const f32x16 zer = {0,0,0,0,0,0,0,0,0,0,0,0,0,0,0,0};
#pragma unroll
    for(int m=0;m<2;m++)
#pragma unroll
        for(int g=0;g<3;g++) acc[m][g]=zer;

#define CVT(d_, va_, vb_) { \
    d_[0]=f2bf(va_.x); d_[1]=f2bf(va_.y); d_[2]=f2bf(va_.z); d_[3]=f2bf(va_.w); \
    d_[4]=f2bf(vb_.x); d_[5]=f2bf(vb_.y); d_[6]=f2bf(vb_.z); d_[7]=f2bf(vb_.w); }

    // ---- r_emb region: 48 ks16 steps (image idx g+8), depth-4 A / depth-2 B pipeline ----
    float4 pa[4][2][2];
    bf16x8 pb[2][3];
#pragma unroll
    for(int p=0;p<4;p++){
        pa[p][0][0]=*(const float4*)(ra0+p*16); pa[p][0][1]=*(const float4*)(ra0+p*16+4);
        pa[p][1][0]=*(const float4*)(ra1+p*16); pa[p][1][1]=*(const float4*)(ra1+p*16+4);
    }
#pragma unroll
    for(int p=0;p<2;p++){
        pb[p][0]=*(const bf16x8*)(wb0+(size_t)(p+8)*512);
        pb[p][1]=*(const bf16x8*)(wb1+(size_t)(p+8)*512);
        pb[p][2]=*(const bf16x8*)(wb2+(size_t)(p+8)*512);
    }
    for(int g0=0; g0<48; g0+=8){
#pragma unroll
        for(int i=0;i<8;i++){
            int g = g0+i;
            int s = i&3, bs = i&1;
            bf16x8 a0, a1;
            CVT(a0, pa[s][0][0], pa[s][0][1]);
            CVT(a1, pa[s][1][0], pa[s][1][1]);
            bf16x8 b0=pb[bs][0], b1=pb[bs][1], b2=pb[bs][2];
            int ga = g+4; if(ga>47) ga=47;
            pa[s][0][0]=*(const float4*)(ra0+ga*16); pa[s][0][1]=*(const float4*)(ra0+ga*16+4);
            pa[s][1][0]=*(const float4*)(ra1+ga*16); pa[s][1][1]=*(const float4*)(ra1+ga*16+4);
            int gb = g+2; if(gb>47) gb=47;
            pb[bs][0]=*(const bf16x8*)(wb0+(size_t)(gb+8)*512);
            pb[bs][1]=*(const bf16x8*)(wb1+(size_t)(gb+8)*512);
            pb[bs][2]=*(const bf16x8*)(wb2+(size_t)(gb+8)*512);
            acc[0][0]=__builtin_amdgcn_mfma_f32_32x32x16_bf16(a0,b0,acc[0][0],0,0,0);
            acc[0][1]=__builtin_amdgcn_mfma_f32_32x32x16_bf16(a0,b1,acc[0][1],0,0,0);
            acc[0][2]=__builtin_amdgcn_mfma_f32_32x32x16_bf16(a0,b2,acc[0][2],0,0,0);
            acc[1][0]=__builtin_amdgcn_mfma_f32_32x32x16_bf16(a1,b0,acc[1][0],0,0,0);
            acc[1][1]=__builtin_amdgcn_mfma_f32_32x32x16_bf16(a1,b1,acc[1][1],0,0,0);
            acc[1][2]=__builtin_amdgcn_mfma_f32_32x32x16_bf16(a1,b2,acc[1][2],0,0,0);
        }
    }

    // ---- z regions: 16 ks16 steps. j<8: z[th] (img idx j); j>=8: z[tt] (img idx j+48) ----
    const ushort* za[2] = { zb + (size_t)th[0]*D2 + lh*8, zb + (size_t)th[1]*D2 + lh*8 };
    const ushort* zc[2] = { zb + (size_t)tt[0]*D2 + lh*8, zb + (size_t)tt[1]*D2 + lh*8 };
#define ZLD(m_,j_) ( (j_)<8 ? *(const bf16x8*)(za[m_]+(j_)*16) : *(const bf16x8*)(zc[m_]+((j_)-8)*16) )
#define ZIMG(j_) ( (j_)<8 ? (j_) : (j_)+48 )
    bf16x8 pz[4][2];
    bf16x8 qb[2][3];
#pragma unroll
    for(int p=0;p<4;p++){ pz[p][0]=ZLD(0,p); pz[p][1]=ZLD(1,p); }
#pragma unroll
    for(int p=0;p<2;p++){
        qb[p][0]=*(const bf16x8*)(wb0+(size_t)ZIMG(p)*512);
        qb[p][1]=*(const bf16x8*)(wb1+(size_t)ZIMG(p)*512);
        qb[p][2]=*(const bf16x8*)(wb2+(size_t)ZIMG(p)*512);
    }
#pragma unroll
    for(int j=0;j<16;j++){
        int s=j&3, bs=j&1;
        bf16x8 a0=pz[s][0], a1=pz[s][1];
        bf16x8 b0=qb[bs][0], b1=qb[bs][1], b2=qb[bs][2];
        if(j+4<16){ pz[s][0]=ZLD(0,j+4); pz[s][1]=ZLD(1,j+4); }
        if(j+2<16){
            qb[bs][0]=*(const bf16x8*)(wb0+(size_t)ZIMG(j+2)*512);
            qb[bs][1]=*(const bf16x8*)(wb1+(size_t)ZIMG(j+2)*512);
            qb[bs][2]=*(const bf16x8*)(wb2+(size_t)ZIMG(j+2)*512);
        }
        acc[0][0]=__builtin_amdgcn_mfma_f32_32x32x16_bf16(a0,b0,acc[0][0],0,0,0);
        acc[0][1]=__builtin_amdgcn_mfma_f32_32x32x16_bf16(a0,b1,acc[0][1],0,0,0);
        acc[0][2]=__builtin_amdgcn_mfma_f32_32x32x16_bf16(a0,b2,acc[0][2],0,0,0);
        acc[1][0]=__builtin_amdgcn_mfma_f32_32x32x16_bf16(a1,b0,acc[1][0],0,0,0);
        acc[1][1]=__builtin_amdgcn_mfma_f32_32x32x16_bf16(a1,b1,acc[1][1],0,0,0);
        acc[1][2]=__builtin_amdgcn_mfma_f32_32x32x16_bf16(a1,b2,acc[1][2],0,0,0);
    }
#undef ZLD
#undef ZIMG
#undef CVT

    // ---- epilogue: bias + LSTM + row-sum reduce ----
    int d = wn*32+l31;
    float bi=b_ih[d]+b_hh[d];
    float bg=b_ih[256+d]+b_hh[256+d];
    float bo=b_ih[384+d]+b_hh[384+d];
#pragma unroll
    for(int m=0;m<2;m++){
#pragma unroll
        for(int r=0;r<16;r++){
            int row = m*32 + (r&3)+8*(r>>2)+4*lh;
            float ig = acc[m][0][r] + bi;
            float gg = acc[m][1][r] + bg;
            float og = acc[m][2][r] + bo;
            float cc = sigf(ig)*tanhfast(gg);
            float ov = sigf(og)*tanhfast(cc);
#pragma unroll
            for(int off=1; off<32; off<<=1) ov += __shfl_xor(ov, off, 64);
            if(l31==0) atomicAdd(&rowsum[row], ov);
        }
    }
    __syncthreads();
    if(tid < BM){
        int t = t0 + tid;
        if(t < T) score[t] = sigf(rowsum[tid]);
    }
}

extern "C" void kernel_launch(void* const* d_in, const int* in_sizes, int n_in,
                              void* d_out, int out_size, void* d_ws, size_t ws_size,
                              hipStream_t stream){
    const float* x    = (const float*)d_in[0];
    const float* remb = (const float*)d_in[1];
    const float* W1   = (const float*)d_in[2];
    const float* b1   = (const float*)d_in[3];
    const float* W2   = (const float*)d_in[4];
    const float* b2   = (const float*)d_in[5];
    const float* Wih  = (const float*)d_in[6];
    const float* b_ih = (const float*)d_in[8];
    const float* b_hh = (const float*)d_in[9];
    const int*   ei   = (const int*)d_in[10];
    const int*   trip = (const int*)d_in[11];
    float* score = (float*)d_out;

    const int N = in_sizes[0]/NF;       // 15000
    const int E = in_sizes[10]/2;       // 200000
    const int T = in_sizes[11]/3;       // 100000
    const int* src = ei;
    const int* dst = ei + E;

    float* ws = (float*)d_ws;
    size_t o = 0;
    ushort* img  = (ushort*)(ws+o); o += (size_t)12*64*64*8/2;   // 786 KB
    ushort* zb   = (ushort*)(ws+o); o += (size_t)N*D2/2;         // 3.84 MB
    int*   cnt    = (int*)(ws+o);   o += (size_t)((N+8)&~7);
    int*   rowptr = (int*)(ws+o);   o += (size_t)((N+8)&~7);
    int*   rowcur = (int*)(ws+o);   o += (size_t)((N+8)&~7);
    int*   esrc   = (int*)(ws+o);   o += (size_t)E;
    float* enorm  = ws+o;           o += (size_t)E;
    float* dinv   = ws+o;           o += (size_t)((N+7)&~7);
    float* h1     = ws+o;           o += (size_t)N*D1;
    float* hbuf   = ws+o;           o += (size_t)N*D1;
    float* hz     = ws+o;           o += (size_t)N*D2;
    (void)ws_size; (void)n_in; (void)out_size;

    hipMemsetAsync(cnt, 0, (size_t)N*sizeof(int), stream);

    k_wimgB<<<dim3((12*64*64+255)/256), dim3(256), 0, stream>>>(Wih, img);
    k_deg  <<<dim3((E+255)/256), dim3(256), 0, stream>>>(dst, cnt, E);
    k_scan <<<dim3(1), dim3(256), 0, stream>>>(cnt, rowptr, rowcur, dinv, N, E);
    k_fill <<<dim3((E+255)/256), dim3(256), 0, stream>>>(src, dst, dinv, rowcur, esrc, enorm, E);
    k_h1   <<<dim3((N+3)/4), dim3(256), 0, stream>>>(x, W1, h1, N);
    k_gath1<<<dim3((N+3)/4), dim3(256), 0, stream>>>(h1, rowptr, esrc, enorm, dinv, b1, hbuf, N);
    k_hz   <<<dim3(N), dim3(128), 0, stream>>>(hbuf, W2, hz, N);
    k_gath2<<<dim3(N), dim3(128), 0, stream>>>(hz, rowptr, esrc, enorm, dinv, b2, zb, N);
    k_big  <<<dim3((T+BM-1)/BM), dim3(256), 0, stream>>>(remb, img, zb, b_ih, b_hh, trip, score, T);
}

// Round 5
// 324.291 us; speedup vs baseline: 2.1095x; 2.1095x over previous
//
#include <hip/hip_runtime.h>

#define NF 768
#define D1 10
#define D2 128
#define BM 64

typedef __attribute__((ext_vector_type(8))) short bf16x8;
typedef __attribute__((ext_vector_type(16))) float f32x16;

static __device__ __forceinline__ float sigf(float v){ return 1.0f/(1.0f+__expf(-v)); }
static __device__ __forceinline__ float tanhfast(float v){ return 2.0f/(1.0f+__expf(-2.0f*v)) - 1.0f; }
static __device__ __forceinline__ short f2bf(float f){
    unsigned u = __float_as_uint(f);
    u += 0x7fffu + ((u>>16)&1u);
    return (short)(u>>16);
}

// ---- degree counts ----
__global__ void k_deg(const int* __restrict__ dst, int* __restrict__ cnt, int E){
    int e = blockIdx.x*256 + threadIdx.x;
    if(e<E) atomicAdd(&cnt[dst[e]], 1);
}

// ---- scan (rowptr/rowcur) + dinv fused, single block ----
__global__ __launch_bounds__(256) void k_scan(const int* __restrict__ cnt,
                                              int* __restrict__ rowptr, int* __restrict__ rowcur,
                                              float* __restrict__ dinv, int N, int E){
    __shared__ int part[256];
    int t = threadIdx.x;
    int C = (N+255)/256;
    int lo = t*C, hi = lo+C; if(hi>N) hi=N; if(lo>N) lo=N;
    int s=0;
    for(int i=lo;i<hi;i++) s += cnt[i];
    part[t]=s;
    __syncthreads();
    if(t==0){
        int run=0;
        for(int i=0;i<256;i++){ int v=part[i]; part[i]=run; run+=v; }
        rowptr[N]=E;
    }
    __syncthreads();
    int run = part[t];
    for(int i=lo;i<hi;i++){
        rowptr[i]=run; rowcur[i]=run; run += cnt[i];
        dinv[i] = rsqrtf((float)cnt[i] + 1.0f);
    }
}

__global__ void k_fill(const int* __restrict__ src, const int* __restrict__ dst,
                       const float* __restrict__ dinv, int* __restrict__ rowcur,
                       int* __restrict__ esrc, float* __restrict__ enorm, int E){
    int e = blockIdx.x*256 + threadIdx.x;
    if(e>=E) return;
    int s=src[e], d=dst[e];
    int pos = atomicAdd(&rowcur[d], 1);
    esrc[pos]=s;
    enorm[pos]=dinv[s]*dinv[d];
}

// ---- h1 = x @ W1 ----
__global__ __launch_bounds__(256) void k_h1(const float* __restrict__ x,
                                            const float* __restrict__ W1,
                                            float* __restrict__ h1, int N){
    __shared__ float wt[D1*NF];
    for(int idx=threadIdx.x; idx<NF*D1; idx+=256){
        int k=idx/D1, c=idx-k*D1;
        wt[c*NF+k]=W1[idx];
    }
    __syncthreads();
    int row = blockIdx.x*4 + (threadIdx.x>>6);
    int lane = threadIdx.x&63;
    if(row>=N) return;
    const float4* xr = (const float4*)(x + (size_t)row*NF);
    float acc[D1];
#pragma unroll
    for(int c=0;c<D1;c++) acc[c]=0.f;
#pragma unroll
    for(int i=0;i<3;i++){
        float4 v = xr[lane + 64*i];
#pragma unroll
        for(int c=0;c<D1;c++){
            float4 w = *(const float4*)&wt[c*NF + (lane+64*i)*4];
            acc[c] += v.x*w.x + v.y*w.y + v.z*w.z + v.w*w.w;
        }
    }
#pragma unroll
    for(int c=0;c<D1;c++){
        float v=acc[c];
#pragma unroll
        for(int off=32;off;off>>=1) v += __shfl_down(v,off,64);
        acc[c]=v;
    }
    if(lane==0){
#pragma unroll
        for(int c=0;c<D1;c++) h1[(size_t)row*D1+c]=acc[c];
    }
}

// ---- layer-1 CSR gather + relu ----
__global__ __launch_bounds__(256) void k_gath1(const float* __restrict__ h1,
        const int* __restrict__ rowptr, const int* __restrict__ esrc,
        const float* __restrict__ enorm, const float* __restrict__ dinv,
        const float* __restrict__ b1, float* __restrict__ h, int N){
    int node = blockIdx.x*4 + (threadIdx.x>>6);
    int lane = threadIdx.x&63;
    if(node>=N) return;
    int e0=rowptr[node], e1=rowptr[node+1];
    float acc[D1];
#pragma unroll
    for(int c=0;c<D1;c++) acc[c]=0.f;
    for(int e=e0+lane; e<e1; e+=64){
        int s=esrc[e]; float w=enorm[e];
        const float* hr = h1 + (size_t)s*D1;
#pragma unroll
        for(int c=0;c<D1;c++) acc[c] += hr[c]*w;
    }
    if(lane==0){
        float di=dinv[node], d2=di*di;
        const float* hr = h1 + (size_t)node*D1;
#pragma unroll
        for(int c=0;c<D1;c++) acc[c] += hr[c]*d2;
    }
#pragma unroll
    for(int c=0;c<D1;c++){
        float v=acc[c];
#pragma unroll
        for(int off=32;off;off>>=1) v += __shfl_down(v,off,64);
        acc[c]=v;
    }
    if(lane==0){
#pragma unroll
        for(int c=0;c<D1;c++){
            float v = acc[c] + b1[c];
            h[(size_t)node*D1+c] = v>0.f ? v : 0.f;
        }
    }
}

__global__ __launch_bounds__(128) void k_hz(const float* __restrict__ h,
                                            const float* __restrict__ W2,
                                            float* __restrict__ hz, int N){
    __shared__ float w2s[D1*D2];
    int j = threadIdx.x;
    for(int i=j;i<D1*D2;i+=128) w2s[i]=W2[i];
    __syncthreads();
    int n = blockIdx.x;
    if(n>=N) return;
    const float* hr = h + (size_t)n*D1;
    float acc=0.f;
#pragma unroll
    for(int k=0;k<D1;k++) acc += hr[k]*w2s[k*D2+j];
    hz[(size_t)n*D2+j]=acc;
}

// ---- layer-2 CSR gather (fused zfin), writes bf16 zb table ----
__global__ __launch_bounds__(128) void k_gath2(const float* __restrict__ hz,
        const int* __restrict__ rowptr, const int* __restrict__ esrc,
        const float* __restrict__ enorm, const float* __restrict__ dinv,
        const float* __restrict__ b2, ushort* __restrict__ zb, int N){
    int n = blockIdx.x;
    int c = threadIdx.x;
    int e0 = rowptr[n], e1 = rowptr[n+1];
    float di = dinv[n];
    float acc = hz[(size_t)n*D2+c]*di*di + b2[c];
    int e = e0;
    for(; e+1<e1; e+=2){
        int s0=esrc[e], s1=esrc[e+1];
        float w0=enorm[e], w1=enorm[e+1];
        acc += hz[(size_t)s0*D2+c]*w0 + hz[(size_t)s1*D2+c]*w1;
    }
    if(e<e1) acc += hz[(size_t)esrc[e]*D2+c]*enorm[e];
    zb[(size_t)n*D2+c] = (ushort)f2bf(acc);
}

// ---- B fragment image over FULL K=1024: 12 frags x 64 ks16 x 64 lanes x 8 bf16 ----
__global__ void k_wimgB(const float* __restrict__ Wih, ushort* __restrict__ img){
    int gid = blockIdx.x*256 + threadIdx.x;        // 12*64*64 = 49152
    if(gid >= 12*64*64) return;
    int l = gid & 63;
    int ks16 = (gid>>6) & 63;
    int f = gid >> 12;
    int dd = l & 31, kb = l>>5;
    int wn = f/3, gi = f - wn*3;
    int gbase = (gi==0)?0:((gi==1)?256:384);
    int wrow = gbase + wn*32 + dd;
    int k = ks16*16 + kb*8;
    const float* p = Wih + (size_t)wrow*1024 + k;
    float4 v0=*(const float4*)p, v1=*(const float4*)(p+4);
    bf16x8 o;
    o[0]=f2bf(v0.x); o[1]=f2bf(v0.y); o[2]=f2bf(v0.z); o[3]=f2bf(v0.w);
    o[4]=f2bf(v1.x); o[5]=f2bf(v1.y); o[6]=f2bf(v1.z); o[7]=f2bf(v1.w);
    *(bf16x8*)(img + (size_t)gid*8) = o;
}

// ---- stage one 256-k chunk of feat = [z_h | r_emb | z_t] into LDS (bf16, XOR-swizzled) ----
// buf layout: row (0..63) * 256 ushort; 32 slots of 8 bf16 per row; slot' = slot ^ (row&7)
static __device__ __forceinline__ void stage_chunk(ushort* __restrict__ buf, int ch,
        int tid, int t0, int T, const float* __restrict__ remb,
        const ushort* __restrict__ zb, const int* __restrict__ trip){
    int row = tid>>2, q = tid&3;
    int tc = t0+row; if(tc>=T) tc=T-1;
    int xr = row&7;
    ushort* lrow = buf + row*256;
    const size_t rb = (size_t)tc*NF;
#pragma unroll
    for(int j=0;j<8;j++){
        int s = q + 4*j;            // slot 0..31
        int G = ch*32 + s;          // global 8-elem group 0..127
        if(G < 16){
            const ushort* zrow = zb + (size_t)trip[3*tc]*D2;
            *(int4*)(lrow + (s^xr)*8) = *(const int4*)(zrow + G*8);
        } else if(G < 112){
            int g = G-16;
            const float* p = remb + rb + (size_t)g*8;
            float4 v0=*(const float4*)p, v1=*(const float4*)(p+4);
            bf16x8 o;
            o[0]=f2bf(v0.x); o[1]=f2bf(v0.y); o[2]=f2bf(v0.z); o[3]=f2bf(v0.w);
            o[4]=f2bf(v1.x); o[5]=f2bf(v1.y); o[6]=f2bf(v1.z); o[7]=f2bf(v1.w);
            *(bf16x8*)(lrow + (s^xr)*8) = o;
        } else {
            const ushort* zrow = zb + (size_t)trip[3*tc+2]*D2;
            *(int4*)(lrow + (s^xr)*8) = *(const int4*)(zrow + (G-112)*8);
        }
    }
}

// ---- fused MFMA GEMM + LSTM. 4 chunks x 16 ks16, double-buffered LDS, 5 barriers ----
__global__ __launch_bounds__(256,2) void k_big(
    const float* __restrict__ remb, const ushort* __restrict__ img,
    const ushort* __restrict__ zb, const float* __restrict__ b_ih,
    const float* __restrict__ b_hh, const int* __restrict__ trip,
    float* __restrict__ score, int T)
{
    __shared__ ushort Abuf[2][64*256];   // 2 x 32 KB
    int tid=threadIdx.x, lane=tid&63, wn=tid>>6;
    int l31=lane&31, lh=lane>>5;
    int t0=blockIdx.x*BM;

    const ushort* wb0 = img + ((size_t)(wn*3+0)*64*64 + lane)*8;
    const ushort* wb1 = img + ((size_t)(wn*3+1)*64*64 + lane)*8;
    const ushort* wb2 = img + ((size_t)(wn*3+2)*64*64 + lane)*8;
    const int base0 = l31*256;
    const int base1 = (32+l31)*256;
    const int xorm = l31&7;

    f32x16 acc[2][3];
    const f32x16 zer = {0,0,0,0,0,0,0,0,0,0,0,0,0,0,0,0};
#pragma unroll
    for(int m=0;m<2;m++)
#pragma unroll
        for(int g=0;g<3;g++) acc[m][g]=zer;

    stage_chunk(Abuf[0], 0, tid, t0, T, remb, zb, trip);
    __syncthreads();

    for(int ch=0; ch<4; ++ch){
        ushort* cur = Abuf[ch&1];
        if(ch<3) stage_chunk(Abuf[(ch+1)&1], ch+1, tid, t0, T, remb, zb, trip);
        // compute 16 ks16 steps from cur
        bf16x8 qb[2][3], pa[2][2];
#pragma unroll
        for(int p=0;p<2;p++){
            int ks = ch*16 + p;
            qb[p][0]=*(const bf16x8*)(wb0+(size_t)ks*512);
            qb[p][1]=*(const bf16x8*)(wb1+(size_t)ks*512);
            qb[p][2]=*(const bf16x8*)(wb2+(size_t)ks*512);
            pa[p][0]=*(const bf16x8*)&cur[base0 + ((p*2+lh)^xorm)*8];
            pa[p][1]=*(const bf16x8*)&cur[base1 + ((p*2+lh)^xorm)*8];
        }
#pragma unroll
        for(int c=0;c<16;c++){
            int bs=c&1;
            bf16x8 a0=pa[bs][0], a1=pa[bs][1];
            bf16x8 b0=qb[bs][0], b1=qb[bs][1], b2=qb[bs][2];
            if(c+2<16){
                int ks = ch*16 + c+2;
                qb[bs][0]=*(const bf16x8*)(wb0+(size_t)ks*512);
                qb[bs][1]=*(const bf16x8*)(wb1+(size_t)ks*512);
                qb[bs][2]=*(const bf16x8*)(wb2+(size_t)ks*512);
                pa[bs][0]=*(const bf16x8*)&cur[base0 + (((c+2)*2+lh)^xorm)*8];
                pa[bs][1]=*(const bf16x8*)&cur[base1 + (((c+2)*2+lh)^xorm)*8];
            }
            acc[0][0]=__builtin_amdgcn_mfma_f32_32x32x16_bf16(a0,b0,acc[0][0],0,0,0);
            acc[0][1]=__builtin_amdgcn_mfma_f32_32x32x16_bf16(a0,b1,acc[0][1],0,0,0);
            acc[0][2]=__builtin_amdgcn_mfma_f32_32x32x16_bf16(a0,b2,acc[0][2],0,0,0);
            acc[1][0]=__builtin_amdgcn_mfma_f32_32x32x16_bf16(a1,b0,acc[1][0],0,0,0);
            acc[1][1]=__builtin_amdgcn_mfma_f32_32x32x16_bf16(a1,b1,acc[1][1],0,0,0);
            acc[1][2]=__builtin_amdgcn_mfma_f32_32x32x16_bf16(a1,b2,acc[1][2],0,0,0);
        }
        __syncthreads();
    }

    // ---- epilogue: bias + LSTM + row-sum reduce (reuse Abuf as rowsum) ----
    float* rowsum = (float*)&Abuf[0][0];
    if(tid<BM) rowsum[tid]=0.f;
    __syncthreads();
    int d = wn*32+l31;
    float bi=b_ih[d]+b_hh[d];
    float bg=b_ih[256+d]+b_hh[256+d];
    float bo=b_ih[384+d]+b_hh[384+d];
#pragma unroll
    for(int m=0;m<2;m++){
#pragma unroll
        for(int r=0;r<16;r++){
            int row = m*32 + (r&3)+8*(r>>2)+4*lh;
            float ig = acc[m][0][r] + bi;
            float gg = acc[m][1][r] + bg;
            float og = acc[m][2][r] + bo;
            float cc = sigf(ig)*tanhfast(gg);
            float ov = sigf(og)*tanhfast(cc);
#pragma unroll
            for(int off=1; off<32; off<<=1) ov += __shfl_xor(ov, off, 64);
            if(l31==0) atomicAdd(&rowsum[row], ov);
        }
    }
    __syncthreads();
    if(tid < BM){
        int t = t0 + tid;
        if(t < T) score[t] = sigf(rowsum[tid]);
    }
}

extern "C" void kernel_launch(void* const* d_in, const int* in_sizes, int n_in,
                              void* d_out, int out_size, void* d_ws, size_t ws_size,
                              hipStream_t stream){
    const float* x    = (const float*)d_in[0];
    const float* remb = (const float*)d_in[1];
    const float* W1   = (const float*)d_in[2];
    const float* b1   = (const float*)d_in[3];
    const float* W2   = (const float*)d_in[4];
    const float* b2   = (const float*)d_in[5];
    const float* Wih  = (const float*)d_in[6];
    const float* b_ih = (const float*)d_in[8];
    const float* b_hh = (const float*)d_in[9];
    const int*   ei   = (const int*)d_in[10];
    const int*   trip = (const int*)d_in[11];
    float* score = (float*)d_out;

    const int N = in_sizes[0]/NF;       // 15000
    const int E = in_sizes[10]/2;       // 200000
    const int T = in_sizes[11]/3;       // 100000
    const int* src = ei;
    const int* dst = ei + E;

    float* ws = (float*)d_ws;
    size_t o = 0;
    ushort* img  = (ushort*)(ws+o); o += (size_t)12*64*64*8/2;   // 786 KB
    ushort* zb   = (ushort*)(ws+o); o += (size_t)N*D2/2;         // 3.84 MB
    int*   cnt    = (int*)(ws+o);   o += (size_t)((N+8)&~7);
    int*   rowptr = (int*)(ws+o);   o += (size_t)((N+8)&~7);
    int*   rowcur = (int*)(ws+o);   o += (size_t)((N+8)&~7);
    int*   esrc   = (int*)(ws+o);   o += (size_t)E;
    float* enorm  = ws+o;           o += (size_t)E;
    float* dinv   = ws+o;           o += (size_t)((N+7)&~7);
    float* h1     = ws+o;           o += (size_t)N*D1;
    float* hbuf   = ws+o;           o += (size_t)N*D1;
    float* hz     = ws+o;           o += (size_t)N*D2;
    (void)ws_size; (void)n_in; (void)out_size;

    hipMemsetAsync(cnt, 0, (size_t)N*sizeof(int), stream);

    k_wimgB<<<dim3((12*64*64+255)/256), dim3(256), 0, stream>>>(Wih, img);
    k_deg  <<<dim3((E+255)/256), dim3(256), 0, stream>>>(dst, cnt, E);
    k_scan <<<dim3(1), dim3(256), 0, stream>>>(cnt, rowptr, rowcur, dinv, N, E);
    k_fill <<<dim3((E+255)/256), dim3(256), 0, stream>>>(src, dst, dinv, rowcur, esrc, enorm, E);
    k_h1   <<<dim3((N+3)/4), dim3(256), 0, stream>>>(x, W1, h1, N);
    k_gath1<<<dim3((N+3)/4), dim3(256), 0, stream>>>(h1, rowptr, esrc, enorm, dinv, b1, hbuf, N);
    k_hz   <<<dim3(N), dim3(128), 0, stream>>>(hbuf, W2, hz, N);
    k_gath2<<<dim3(N), dim3(128), 0, stream>>>(hz, rowptr, esrc, enorm, dinv, b2, zb, N);
    k_big  <<<dim3((T+BM-1)/BM), dim3(256), 0, stream>>>(remb, img, zb, b_ih, b_hh, trip, score, T);
}